// Round 2
// 428.055 us; speedup vs baseline: 1.0530x; 1.0530x over previous
//
#include <hip/hip_runtime.h>
#include <hip/hip_bf16.h>
#include <stdint.h>

#define NN 4096
#define EPSV 1e-7f

typedef short shortx4 __attribute__((ext_vector_type(4)));
typedef short short8 __attribute__((ext_vector_type(8)));
typedef float floatx2 __attribute__((ext_vector_type(2)));
typedef float floatx4 __attribute__((ext_vector_type(4)));
typedef int intx4 __attribute__((ext_vector_type(4)));

__device__ __forceinline__ float bf2f(short s) {
    union { unsigned u; float f; } c;
    c.u = ((unsigned)(unsigned short)s) << 16;
    return c.f;
}
__device__ __forceinline__ short f2bf(float f) {
    union { float f; unsigned u; } c;
    c.f = f;
    unsigned r = (c.u + 0x7fffu + ((c.u >> 16) & 1u)) >> 16;
    return (short)r;
}

// Read x once -> xf8 (fp8 e4m3 row-major), xb (bf16 row-major), nsq (f32 col sumsq).
// v2: fully vectorized — float4 loads, shortx4 (8B) + packed-int (4B) stores.
__global__ __launch_bounds__(256) void fuse_cast(const float* __restrict__ x,
                                                 unsigned char* __restrict__ xf8,
                                                 short* __restrict__ xb,
                                                 float* __restrict__ nsq) {
    __shared__ floatx4 cs[4][64];
    const int tx = threadIdx.x;       // 0..63
    const int ty = threadIdx.y;       // 0..3
    const int cb = blockIdx.x * 256;  // 16 blocks cover 4096 cols
    const int rb = blockIdx.y * 64;   // 64 blocks cover 4096 rows
    const int col = cb + tx * 4;
    floatx4 ss = {0.f, 0.f, 0.f, 0.f};
#pragma unroll
    for (int i = 0; i < 16; ++i) {
        const int r = rb + ty + i * 4;
        floatx4 v = *(const floatx4*)(x + (size_t)r * NN + col);
        ss += v * v;
        shortx4 o;
        o[0] = f2bf(v[0]); o[1] = f2bf(v[1]); o[2] = f2bf(v[2]); o[3] = f2bf(v[3]);
        *(shortx4*)(xb + (size_t)r * NN + col) = o;
        int p = __builtin_amdgcn_cvt_pk_fp8_f32(v[0], v[1], 0, false);
        p = __builtin_amdgcn_cvt_pk_fp8_f32(v[2], v[3], p, true);
        *(int*)(xf8 + (size_t)r * NN + col) = p;
    }
    cs[ty][tx] = ss;
    __syncthreads();
    if (ty == 0) {
        floatx4 s4 = cs[0][tx] + cs[1][tx] + cs[2][tx] + cs[3][tx];
        float* np = nsq + col;
        atomicAdd(np + 0, s4[0]);
        atomicAdd(np + 1, s4[1]);
        atomicAdd(np + 2, s4[2]);
        atomicAdd(np + 3, s4[3]);
    }
}

// One block per output row i. build_idx is fused (adj row scanned with float4,
// loads issued before the first barrier so they overlap x_i staging).
//   A: s_k = beta*(x_i . x_jk)/(n_i n_jk + eps), x_i bf16->f32 (LDS), x_jk fp8 gather
//      unrolled 2 k's/wave: 8 b128 loads in flight, shared xi LDS reads,
//      interleaved shuffle-reduce chains.
//   B: softmax over the k's (masked entries contribute exactly 0, as in ref)
//   C: out_i = sum_k p_k * xb_jk — unrolled 4 k's: 8 b128 loads in flight/thread.
// x_i LDS uses granule swizzle g^((g>>3)&7): raw layout would put all even
// lanes of a b128 dot-read in the same 4 banks (32-way conflict).
__global__ __launch_bounds__(256) void sparse_attn(const unsigned char* __restrict__ x8,
                                                   const short* __restrict__ xb,
                                                   const float* __restrict__ nsq,
                                                   const float* __restrict__ adj,
                                                   const float* __restrict__ betaPtr,
                                                   float* __restrict__ out) {
    __shared__ __align__(16) float xi[4096];  // x_i in f32, swizzled granules
    __shared__ float sv[256];                 // scores -> probabilities
    __shared__ unsigned short sidx[256];
    __shared__ int ctr;
    const int t = threadIdx.x;
    const int lane = t & 63;
    const int w = t >> 6;
    const size_t i = blockIdx.x;

    if (t == 0) ctr = 0;

    // issue adj row loads early; consumed after the first barrier
    const floatx4* ar = (const floatx4*)(adj + i * NN);
    floatx4 a0 = ar[t];
    floatx4 a1 = ar[t + 256];
    floatx4 a2 = ar[t + 512];
    floatx4 a3 = ar[t + 768];

    {   // stage x_i from bf16 (8 KB read), swizzled: granule g at g^((g>>3)&7)
        const short8* xr = (const short8*)(xb + i * NN);
        floatx4* xl = (floatx4*)xi;
#pragma unroll
        for (int r = 0; r < 2; ++r) {
            const int m = t + 256 * r;
            short8 v = xr[m];
            const int g0 = 2 * m, g1 = 2 * m + 1;
            floatx4 f0 = {bf2f(v[0]), bf2f(v[1]), bf2f(v[2]), bf2f(v[3])};
            floatx4 f1 = {bf2f(v[4]), bf2f(v[5]), bf2f(v[6]), bf2f(v[7])};
            xl[g0 ^ ((g0 >> 3) & 7)] = f0;
            xl[g1 ^ ((g1 >> 3) & 7)] = f1;
        }
    }
    __syncthreads();  // ctr=0 visible; xi staged

    // build neighbor index list from adj row (order nondeterministic — only
    // affects fp summation order, as before)
#pragma unroll
    for (int q = 0; q < 4; ++q) {
        floatx4 a = (q == 0) ? a0 : (q == 1) ? a1 : (q == 2) ? a2 : a3;
        const int base = (t + 256 * q) * 4;
#pragma unroll
        for (int u = 0; u < 4; ++u) {
            if (a[u] != 0.f) {
                int p = atomicAdd(&ctr, 1);
                if (p < 256) sidx[p] = (unsigned short)(base + u);
            }
        }
    }
    __syncthreads();
    const int c = ctr > 256 ? 256 : ctr;

    const float beta = *betaPtr;
    const float ni = sqrtf(nsq[i]);

    // phase A: wave w handles k = w, w+4, ... ; 2 k's per iteration
    const floatx4* xi4 = (const floatx4*)xi;
    for (int k = w; k < c; k += 8) {
        const int k1 = k + 4;
        const bool h1 = k1 < c;
        const int j0 = sidx[k];
        const int j1 = h1 ? sidx[k1] : j0;
        const intx4* p0 = (const intx4*)(x8 + (size_t)j0 * NN);
        const intx4* p1 = (const intx4*)(x8 + (size_t)j1 * NN);
        intx4 A0 = p0[lane], A1 = p0[lane + 64], A2 = p0[lane + 128], A3 = p0[lane + 192];
        intx4 B0 = p1[lane], B1 = p1[lane + 64], B2 = p1[lane + 128], B3 = p1[lane + 192];
        float d0 = 0.f, d1 = 0.f;
#pragma unroll
        for (int r = 0; r < 4; ++r) {
            const int gb = (lane + 64 * r) * 4;
            const int s = (gb >> 3) & 7;
            intx4 a = (r == 0) ? A0 : (r == 1) ? A1 : (r == 2) ? A2 : A3;
            intx4 b = (r == 0) ? B0 : (r == 1) ? B1 : (r == 2) ? B2 : B3;
#pragma unroll
            for (int u = 0; u < 4; ++u) {
                floatx4 bv = xi4[(gb + u) ^ s];
                floatx2 lo = __builtin_amdgcn_cvt_pk_f32_fp8(a[u], false);
                floatx2 hi = __builtin_amdgcn_cvt_pk_f32_fp8(a[u], true);
                d0 = fmaf(lo[0], bv[0], d0);
                d0 = fmaf(lo[1], bv[1], d0);
                d0 = fmaf(hi[0], bv[2], d0);
                d0 = fmaf(hi[1], bv[3], d0);
                floatx2 lo1 = __builtin_amdgcn_cvt_pk_f32_fp8(b[u], false);
                floatx2 hi1 = __builtin_amdgcn_cvt_pk_f32_fp8(b[u], true);
                d1 = fmaf(lo1[0], bv[0], d1);
                d1 = fmaf(lo1[1], bv[1], d1);
                d1 = fmaf(hi1[0], bv[2], d1);
                d1 = fmaf(hi1[1], bv[3], d1);
            }
        }
        // interleaved butterfly reduces (two independent chains)
#pragma unroll
        for (int off = 32; off; off >>= 1) {
            d0 += __shfl_xor(d0, off, 64);
            d1 += __shfl_xor(d1, off, 64);
        }
        if (lane == 0) {
            sv[k] = beta * d0 / (ni * sqrtf(nsq[j0]) + EPSV);
            if (h1) sv[k1] = beta * d1 / (ni * sqrtf(nsq[j1]) + EPSV);
        }
    }
    __syncthreads();

    // phase B: wave 0 softmax over sv[0..c)
    if (w == 0) {
        float mx = -3.0e38f;
        for (int k = lane; k < c; k += 64) mx = fmaxf(mx, sv[k]);
#pragma unroll
        for (int off = 32; off; off >>= 1) mx = fmaxf(mx, __shfl_xor(mx, off, 64));
        float sm = 0.f;
        for (int k = lane; k < c; k += 64) {
            float e = __expf(sv[k] - mx);
            sv[k] = e;
            sm += e;
        }
#pragma unroll
        for (int off = 32; off; off >>= 1) sm += __shfl_xor(sm, off, 64);
        const float inv = 1.f / sm;
        for (int k = lane; k < c; k += 64) sv[k] *= inv;
    }
    __syncthreads();

    // phase C: thread t accumulates out[i][16t .. 16t+16), 4 k's per iteration
    float acc[16];
#pragma unroll
    for (int e = 0; e < 16; ++e) acc[e] = 0.f;
    int k = 0;
    for (; k + 4 <= c; k += 4) {
        const int j0 = sidx[k], j1 = sidx[k + 1], j2 = sidx[k + 2], j3 = sidx[k + 3];
        const float p0 = sv[k], p1 = sv[k + 1], p2 = sv[k + 2], p3 = sv[k + 3];
        const short8* q0 = (const short8*)(xb + (size_t)j0 * NN) + 2 * t;
        const short8* q1 = (const short8*)(xb + (size_t)j1 * NN) + 2 * t;
        const short8* q2 = (const short8*)(xb + (size_t)j2 * NN) + 2 * t;
        const short8* q3 = (const short8*)(xb + (size_t)j3 * NN) + 2 * t;
        short8 v00 = q0[0], v01 = q0[1];
        short8 v10 = q1[0], v11 = q1[1];
        short8 v20 = q2[0], v21 = q2[1];
        short8 v30 = q3[0], v31 = q3[1];
#pragma unroll
        for (int e = 0; e < 8; ++e) {
            float t0 = fmaf(p0, bf2f(v00[e]), acc[e]);
            t0 = fmaf(p1, bf2f(v10[e]), t0);
            t0 = fmaf(p2, bf2f(v20[e]), t0);
            acc[e] = fmaf(p3, bf2f(v30[e]), t0);
            float t1 = fmaf(p0, bf2f(v01[e]), acc[8 + e]);
            t1 = fmaf(p1, bf2f(v11[e]), t1);
            t1 = fmaf(p2, bf2f(v21[e]), t1);
            acc[8 + e] = fmaf(p3, bf2f(v31[e]), t1);
        }
    }
    for (; k < c; ++k) {
        const int j = sidx[k];
        const float p = sv[k];
        const short8* q = (const short8*)(xb + (size_t)j * NN) + 2 * t;
        short8 v0 = q[0], v1 = q[1];
#pragma unroll
        for (int e = 0; e < 8; ++e) {
            acc[e] = fmaf(p, bf2f(v0[e]), acc[e]);
            acc[8 + e] = fmaf(p, bf2f(v1[e]), acc[8 + e]);
        }
    }
    floatx4* op = (floatx4*)(out + i * NN + t * 16);
#pragma unroll
    for (int u = 0; u < 4; ++u)
        op[u] = (floatx4){acc[4 * u], acc[4 * u + 1], acc[4 * u + 2], acc[4 * u + 3]};
}

extern "C" void kernel_launch(void* const* d_in, const int* in_sizes, int n_in,
                              void* d_out, int out_size, void* d_ws, size_t ws_size,
                              hipStream_t stream) {
    const float* x = (const float*)d_in[0];
    const float* adj = (const float*)d_in[1];
    const float* beta = (const float*)d_in[2];

    const size_t MB32 = (size_t)32 * 1024 * 1024;
    const size_t MB16 = (size_t)16 * 1024 * 1024;
    const size_t need = MB32 + MB16 + NN * sizeof(float);
    if (ws_size < need) return;  // ~48 MB

    char* ws = (char*)d_ws;
    short* xb = (short*)ws;                            // bf16 x    32 MB
    unsigned char* xf8 = (unsigned char*)(ws + MB32);  // fp8 x     16 MB
    float* nsq = (float*)(ws + MB32 + MB16);           // col sumsq 16 KB

    (void)hipMemsetAsync(nsq, 0, NN * sizeof(float), stream);
    fuse_cast<<<dim3(16, 64), dim3(64, 4), 0, stream>>>(x, xf8, xb, nsq);
    sparse_attn<<<NN, 256, 0, stream>>>(xf8, xb, nsq, adj, beta, (float*)d_out);
}

// Round 3
// 426.444 us; speedup vs baseline: 1.0569x; 1.0038x over previous
//
#include <hip/hip_runtime.h>
#include <hip/hip_bf16.h>
#include <stdint.h>

#define NN 4096
#define EPSV 1e-7f

typedef short shortx4 __attribute__((ext_vector_type(4)));
typedef short short8 __attribute__((ext_vector_type(8)));
typedef float floatx2 __attribute__((ext_vector_type(2)));
typedef float floatx4 __attribute__((ext_vector_type(4)));
typedef int intx4 __attribute__((ext_vector_type(4)));

__device__ __forceinline__ float bf2f(short s) {
    union { unsigned u; float f; } c;
    c.u = ((unsigned)(unsigned short)s) << 16;
    return c.f;
}
__device__ __forceinline__ short f2bf(float f) {
    union { float f; unsigned u; } c;
    c.f = f;
    unsigned r = (c.u + 0x7fffu + ((c.u >> 16) & 1u)) >> 16;
    return (short)r;
}

// Read x once -> xf8 (fp8 e4m3 row-major), xb (bf16 row-major), nsq (f32 col sumsq).
// x loads are nontemporal: x is never re-read; keep L3 for xb/xf8 residency.
__global__ __launch_bounds__(256) void fuse_cast(const float* __restrict__ x,
                                                 unsigned char* __restrict__ xf8,
                                                 short* __restrict__ xb,
                                                 float* __restrict__ nsq) {
    __shared__ floatx4 cs[4][64];
    const int tx = threadIdx.x;       // 0..63
    const int ty = threadIdx.y;       // 0..3
    const int cb = blockIdx.x * 256;  // 16 blocks cover 4096 cols
    const int rb = blockIdx.y * 64;   // 64 blocks cover 4096 rows
    const int col = cb + tx * 4;
    floatx4 ss = {0.f, 0.f, 0.f, 0.f};
#pragma unroll
    for (int i = 0; i < 16; ++i) {
        const int r = rb + ty + i * 4;
        floatx4 v = __builtin_nontemporal_load((const floatx4*)(x + (size_t)r * NN + col));
        ss += v * v;
        shortx4 o;
        o[0] = f2bf(v[0]); o[1] = f2bf(v[1]); o[2] = f2bf(v[2]); o[3] = f2bf(v[3]);
        *(shortx4*)(xb + (size_t)r * NN + col) = o;
        int p = __builtin_amdgcn_cvt_pk_fp8_f32(v[0], v[1], 0, false);
        p = __builtin_amdgcn_cvt_pk_fp8_f32(v[2], v[3], p, true);
        *(int*)(xf8 + (size_t)r * NN + col) = p;
    }
    cs[ty][tx] = ss;
    __syncthreads();
    if (ty == 0) {
        floatx4 s4 = cs[0][tx] + cs[1][tx] + cs[2][tx] + cs[3][tx];
        float* np = nsq + col;
        atomicAdd(np + 0, s4[0]);
        atomicAdd(np + 1, s4[1]);
        atomicAdd(np + 2, s4[2]);
        atomicAdd(np + 3, s4[3]);
    }
}

// One block per output row i.
// sidx is built SORTED by j via a prefix-sum compaction (thread t owns the 16
// contiguous columns [16t,16t+16)): concurrent waves then gather ADJACENT rows
// -> DRAM page locality + tighter L2/L3 re-reference distance. Deterministic
// (no atomics). adj loads and out stores are nontemporal: pure streams must
// not evict the 48 MB gather working set (xb+xf8) from L2/L3.
//   A: s_k = beta*(x_i . x_jk)/(n_i n_jk + eps), x_i bf16->f32 (LDS), x_jk fp8 gather
//   B: softmax over the k's (masked entries contribute exactly 0, as in ref)
//   C: out_i = sum_k p_k * xb_jk — unrolled 4 k's, f32 accumulate.
// x_i LDS uses granule swizzle g^((g>>3)&7): raw layout would put all even
// lanes of a b128 dot-read in the same 4 banks (32-way conflict).
__global__ __launch_bounds__(256) void sparse_attn(const unsigned char* __restrict__ x8,
                                                   const short* __restrict__ xb,
                                                   const float* __restrict__ nsq,
                                                   const float* __restrict__ adj,
                                                   const float* __restrict__ betaPtr,
                                                   float* __restrict__ out) {
    __shared__ __align__(16) float xi[4096];  // x_i in f32, swizzled granules
    __shared__ float sv[256];                 // scores -> probabilities
    __shared__ unsigned short sidx[256];
    __shared__ int wtot[4];
    const int t = threadIdx.x;
    const int lane = t & 63;
    const int w = t >> 6;
    const size_t i = blockIdx.x;

    // issue adj segment loads early (nontemporal); thread t owns cols [16t,16t+16)
    const floatx4* ar = (const floatx4*)(adj + i * NN) + 4 * t;
    floatx4 a0 = __builtin_nontemporal_load(ar + 0);
    floatx4 a1 = __builtin_nontemporal_load(ar + 1);
    floatx4 a2 = __builtin_nontemporal_load(ar + 2);
    floatx4 a3 = __builtin_nontemporal_load(ar + 3);

    {   // stage x_i from bf16 (8 KB read), swizzled: granule g at g^((g>>3)&7)
        const short8* xr = (const short8*)(xb + i * NN);
        floatx4* xl = (floatx4*)xi;
#pragma unroll
        for (int r = 0; r < 2; ++r) {
            const int m = t + 256 * r;
            short8 v = xr[m];
            const int g0 = 2 * m, g1 = 2 * m + 1;
            floatx4 f0 = {bf2f(v[0]), bf2f(v[1]), bf2f(v[2]), bf2f(v[3])};
            floatx4 f1 = {bf2f(v[4]), bf2f(v[5]), bf2f(v[6]), bf2f(v[7])};
            xl[g0 ^ ((g0 >> 3) & 7)] = f0;
            xl[g1 ^ ((g1 >> 3) & 7)] = f1;
        }
    }

    // build hit mask over the 16 owned columns, then prefix-sum compaction
    unsigned mask = 0;
#pragma unroll
    for (int u = 0; u < 4; ++u) {
        floatx4 a = (u == 0) ? a0 : (u == 1) ? a1 : (u == 2) ? a2 : a3;
#pragma unroll
        for (int e = 0; e < 4; ++e)
            if (a[e] != 0.f) mask |= 1u << (4 * u + e);
    }
    const int h = __popc(mask);
    int sc = h;  // wave-inclusive scan
#pragma unroll
    for (int o = 1; o < 64; o <<= 1) {
        int v = __shfl_up(sc, o, 64);
        if (lane >= o) sc += v;
    }
    if (lane == 63) wtot[w] = sc;
    __syncthreads();  // wtot + xi staged
    int base = 0;
#pragma unroll
    for (int ww = 0; ww < 4; ++ww)
        if (ww < w) base += wtot[ww];
    int c = wtot[0] + wtot[1] + wtot[2] + wtot[3];
    if (c > 256) c = 256;
    {
        int off = base + sc - h;  // exclusive prefix
        unsigned m = mask;
        while (m) {
            int b = __ffs(m) - 1;
            m &= m - 1;
            if (off < 256) sidx[off] = (unsigned short)(16 * t + b);
            ++off;
        }
    }
    __syncthreads();  // sidx ready (sorted ascending by j)

    const float beta = *betaPtr;
    const float ni = sqrtf(nsq[i]);

    // phase A: wave w handles k = w, w+4, ... ; 2 k's per iteration
    const floatx4* xi4 = (const floatx4*)xi;
    for (int k = w; k < c; k += 8) {
        const int k1 = k + 4;
        const bool h1 = k1 < c;
        const int j0 = sidx[k];
        const int j1 = h1 ? sidx[k1] : j0;
        const intx4* p0 = (const intx4*)(x8 + (size_t)j0 * NN);
        const intx4* p1 = (const intx4*)(x8 + (size_t)j1 * NN);
        intx4 A0 = p0[lane], A1 = p0[lane + 64], A2 = p0[lane + 128], A3 = p0[lane + 192];
        intx4 B0 = p1[lane], B1 = p1[lane + 64], B2 = p1[lane + 128], B3 = p1[lane + 192];
        float d0 = 0.f, d1 = 0.f;
#pragma unroll
        for (int r = 0; r < 4; ++r) {
            const int gb = (lane + 64 * r) * 4;
            const int s = (gb >> 3) & 7;
            intx4 a = (r == 0) ? A0 : (r == 1) ? A1 : (r == 2) ? A2 : A3;
            intx4 b = (r == 0) ? B0 : (r == 1) ? B1 : (r == 2) ? B2 : B3;
#pragma unroll
            for (int u = 0; u < 4; ++u) {
                floatx4 bv = xi4[(gb + u) ^ s];
                floatx2 lo = __builtin_amdgcn_cvt_pk_f32_fp8(a[u], false);
                floatx2 hi = __builtin_amdgcn_cvt_pk_f32_fp8(a[u], true);
                d0 = fmaf(lo[0], bv[0], d0);
                d0 = fmaf(lo[1], bv[1], d0);
                d0 = fmaf(hi[0], bv[2], d0);
                d0 = fmaf(hi[1], bv[3], d0);
                floatx2 lo1 = __builtin_amdgcn_cvt_pk_f32_fp8(b[u], false);
                floatx2 hi1 = __builtin_amdgcn_cvt_pk_f32_fp8(b[u], true);
                d1 = fmaf(lo1[0], bv[0], d1);
                d1 = fmaf(lo1[1], bv[1], d1);
                d1 = fmaf(hi1[0], bv[2], d1);
                d1 = fmaf(hi1[1], bv[3], d1);
            }
        }
#pragma unroll
        for (int off = 32; off; off >>= 1) {
            d0 += __shfl_xor(d0, off, 64);
            d1 += __shfl_xor(d1, off, 64);
        }
        if (lane == 0) {
            sv[k] = beta * d0 / (ni * sqrtf(nsq[j0]) + EPSV);
            if (h1) sv[k1] = beta * d1 / (ni * sqrtf(nsq[j1]) + EPSV);
        }
    }
    __syncthreads();

    // phase B: wave 0 softmax over sv[0..c)
    if (w == 0) {
        float mx = -3.0e38f;
        for (int k = lane; k < c; k += 64) mx = fmaxf(mx, sv[k]);
#pragma unroll
        for (int off = 32; off; off >>= 1) mx = fmaxf(mx, __shfl_xor(mx, off, 64));
        float sm = 0.f;
        for (int k = lane; k < c; k += 64) {
            float e = __expf(sv[k] - mx);
            sv[k] = e;
            sm += e;
        }
#pragma unroll
        for (int off = 32; off; off >>= 1) sm += __shfl_xor(sm, off, 64);
        const float inv = 1.f / sm;
        for (int k = lane; k < c; k += 64) sv[k] *= inv;
    }
    __syncthreads();

    // phase C: thread t accumulates out[i][16t .. 16t+16), 4 k's per iteration
    float acc[16];
#pragma unroll
    for (int e = 0; e < 16; ++e) acc[e] = 0.f;
    int k = 0;
    for (; k + 4 <= c; k += 4) {
        const int j0 = sidx[k], j1 = sidx[k + 1], j2 = sidx[k + 2], j3 = sidx[k + 3];
        const float p0 = sv[k], p1 = sv[k + 1], p2 = sv[k + 2], p3 = sv[k + 3];
        const short8* q0 = (const short8*)(xb + (size_t)j0 * NN) + 2 * t;
        const short8* q1 = (const short8*)(xb + (size_t)j1 * NN) + 2 * t;
        const short8* q2 = (const short8*)(xb + (size_t)j2 * NN) + 2 * t;
        const short8* q3 = (const short8*)(xb + (size_t)j3 * NN) + 2 * t;
        short8 v00 = q0[0], v01 = q0[1];
        short8 v10 = q1[0], v11 = q1[1];
        short8 v20 = q2[0], v21 = q2[1];
        short8 v30 = q3[0], v31 = q3[1];
#pragma unroll
        for (int e = 0; e < 8; ++e) {
            float t0 = fmaf(p0, bf2f(v00[e]), acc[e]);
            t0 = fmaf(p1, bf2f(v10[e]), t0);
            t0 = fmaf(p2, bf2f(v20[e]), t0);
            acc[e] = fmaf(p3, bf2f(v30[e]), t0);
            float t1 = fmaf(p0, bf2f(v01[e]), acc[8 + e]);
            t1 = fmaf(p1, bf2f(v11[e]), t1);
            t1 = fmaf(p2, bf2f(v21[e]), t1);
            acc[8 + e] = fmaf(p3, bf2f(v31[e]), t1);
        }
    }
    for (; k < c; ++k) {
        const int j = sidx[k];
        const float p = sv[k];
        const short8* q = (const short8*)(xb + (size_t)j * NN) + 2 * t;
        short8 v0 = q[0], v1 = q[1];
#pragma unroll
        for (int e = 0; e < 8; ++e) {
            acc[e] = fmaf(p, bf2f(v0[e]), acc[e]);
            acc[8 + e] = fmaf(p, bf2f(v1[e]), acc[8 + e]);
        }
    }
    floatx4* op = (floatx4*)(out + i * NN + t * 16);
#pragma unroll
    for (int u = 0; u < 4; ++u) {
        floatx4 v = {acc[4 * u], acc[4 * u + 1], acc[4 * u + 2], acc[4 * u + 3]};
        __builtin_nontemporal_store(v, op + u);
    }
}

extern "C" void kernel_launch(void* const* d_in, const int* in_sizes, int n_in,
                              void* d_out, int out_size, void* d_ws, size_t ws_size,
                              hipStream_t stream) {
    const float* x = (const float*)d_in[0];
    const float* adj = (const float*)d_in[1];
    const float* beta = (const float*)d_in[2];

    const size_t MB32 = (size_t)32 * 1024 * 1024;
    const size_t MB16 = (size_t)16 * 1024 * 1024;
    const size_t need = MB32 + MB16 + NN * sizeof(float);
    if (ws_size < need) return;  // ~48 MB

    char* ws = (char*)d_ws;
    short* xb = (short*)ws;                            // bf16 x    32 MB
    unsigned char* xf8 = (unsigned char*)(ws + MB32);  // fp8 x     16 MB
    float* nsq = (float*)(ws + MB32 + MB16);           // col sumsq 16 KB

    (void)hipMemsetAsync(nsq, 0, NN * sizeof(float), stream);
    fuse_cast<<<dim3(16, 64), dim3(64, 4), 0, stream>>>(x, xf8, xb, nsq);
    sparse_attn<<<NN, 256, 0, stream>>>(xf8, xb, nsq, adj, beta, (float*)d_out);
}

// Round 4
// 403.759 us; speedup vs baseline: 1.1163x; 1.0562x over previous
//
#include <hip/hip_runtime.h>
#include <stdint.h>

#define NN 4096
#define EPSV 1e-7f
#define SLABC 512          // columns per slab; 4096x512 bf16 = 4 MB = one XCD L2
#define NSLAB (NN / SLABC) // 8 slabs = 8 XCDs

typedef short shortx4 __attribute__((ext_vector_type(4)));
typedef short short8 __attribute__((ext_vector_type(8)));
typedef float floatx2 __attribute__((ext_vector_type(2)));
typedef float floatx4 __attribute__((ext_vector_type(4)));

static __device__ __forceinline__ float bf2f(short s) {
    union { unsigned u; float f; } c;
    c.u = ((unsigned)(unsigned short)s) << 16;
    return c.f;
}
static __device__ __forceinline__ short f2bf(float f) {
    union { float f; unsigned u; } c;
    c.f = f;
    unsigned r = (c.u + 0x7fffu + ((c.u >> 16) & 1u)) >> 16;
    return (short)r;
}

// x (f32) -> xb (bf16 row-major) + nsq (col sumsq). x never re-read -> nt loads.
__global__ __launch_bounds__(256) void fuse_cast(const float* __restrict__ x,
                                                 short* __restrict__ xb,
                                                 float* __restrict__ nsq) {
    __shared__ floatx4 cs[4][64];
    const int tx = threadIdx.x;       // 0..63
    const int ty = threadIdx.y;       // 0..3
    const int cb = blockIdx.x * 256;  // 16 blocks cover 4096 cols
    const int rb = blockIdx.y * 64;   // 64 blocks cover 4096 rows
    const int col = cb + tx * 4;
    floatx4 ss = {0.f, 0.f, 0.f, 0.f};
#pragma unroll
    for (int i = 0; i < 16; ++i) {
        const int r = rb + ty + i * 4;
        floatx4 v = __builtin_nontemporal_load((const floatx4*)(x + (size_t)r * NN + col));
        ss += v * v;
        shortx4 o;
        o[0] = f2bf(v[0]); o[1] = f2bf(v[1]); o[2] = f2bf(v[2]); o[3] = f2bf(v[3]);
        *(shortx4*)(xb + (size_t)r * NN + col) = o;
    }
    cs[ty][tx] = ss;
    __syncthreads();
    if (ty == 0) {
        floatx4 s4 = cs[0][tx] + cs[1][tx] + cs[2][tx] + cs[3][tx];
        float* np = nsq + col;
        atomicAdd(np + 0, s4[0]);
        atomicAdd(np + 1, s4[1]);
        atomicAdd(np + 2, s4[2]);
        atomicAdd(np + 3, s4[3]);
    }
}

// adj row i -> sorted column-index list (prefix-sum compaction, deterministic).
// Thread t owns cols [16t, 16t+16). ~42 nnz/row; cap 256 is +33 sigma.
__global__ __launch_bounds__(256) void build_idx(const float* __restrict__ adj,
                                                 unsigned short* __restrict__ idx,
                                                 int* __restrict__ cnt) {
    __shared__ int wtot[4];
    const int t = threadIdx.x;
    const int lane = t & 63;
    const int w = t >> 6;
    const size_t i = blockIdx.x;
    const floatx4* ar = (const floatx4*)(adj + i * NN) + 4 * t;
    floatx4 a0 = __builtin_nontemporal_load(ar + 0);
    floatx4 a1 = __builtin_nontemporal_load(ar + 1);
    floatx4 a2 = __builtin_nontemporal_load(ar + 2);
    floatx4 a3 = __builtin_nontemporal_load(ar + 3);
    unsigned mask = 0;
#pragma unroll
    for (int u = 0; u < 4; ++u) {
        floatx4 a = (u == 0) ? a0 : (u == 1) ? a1 : (u == 2) ? a2 : a3;
#pragma unroll
        for (int e = 0; e < 4; ++e)
            if (a[e] != 0.f) mask |= 1u << (4 * u + e);
    }
    const int h = __popc(mask);
    int sc = h;  // wave-inclusive scan
#pragma unroll
    for (int o = 1; o < 64; o <<= 1) {
        int v = __shfl_up(sc, o, 64);
        if (lane >= o) sc += v;
    }
    if (lane == 63) wtot[w] = sc;
    __syncthreads();
    int base = 0;
#pragma unroll
    for (int ww = 0; ww < 4; ++ww)
        if (ww < w) base += wtot[ww];
    int c = wtot[0] + wtot[1] + wtot[2] + wtot[3];
    if (c > 256) c = 256;
    if (t == 0) cnt[i] = c;
    int off = base + sc - h;  // exclusive prefix
    unsigned m = mask;
    while (m) {
        int b = __ffs(m) - 1;
        m &= m - 1;
        if (off < 256) idx[i * 256 + off] = (unsigned short)(16 * t + b);
        ++off;
    }
}

// Partial scores for one (i, slab): score[i][k] += x_i[slab] . x_jk[slab].
// gridDim.x = NSLAB so workgroup n -> XCD n%8 -> XCD s only touches slab s of
// xb (4 MB, L2-resident). Lane l owns cols [8l, 8l+8) of the slab: x_i slice
// lives in 8 registers — no LDS, no barrier. 2 k's in flight per wave.
__global__ __launch_bounds__(256) void score_slab(const short* __restrict__ xb,
                                                  const unsigned short* __restrict__ idx,
                                                  const int* __restrict__ cnt,
                                                  float* __restrict__ score) {
    const int t = threadIdx.x;
    const int lane = t & 63;
    const int w = t >> 6;
    const int col0 = blockIdx.x * SLABC;
    const size_t i = blockIdx.y;
    const int c = cnt[i];

    short8 vx = ((const short8*)(xb + i * NN + col0))[lane];
    float xi[8];
#pragma unroll
    for (int e = 0; e < 8; ++e) xi[e] = bf2f(vx[e]);

    const unsigned short* irow = idx + i * 256;
    for (int k = w; k < c; k += 8) {
        const int k1 = k + 4;
        const bool h1 = k1 < c;
        const int j0 = irow[k];
        const int j1 = h1 ? irow[k1] : j0;
        short8 v0 = ((const short8*)(xb + (size_t)j0 * NN + col0))[lane];
        short8 v1 = ((const short8*)(xb + (size_t)j1 * NN + col0))[lane];
        float d0 = 0.f, d1 = 0.f;
#pragma unroll
        for (int e = 0; e < 8; ++e) {
            d0 = fmaf(bf2f(v0[e]), xi[e], d0);
            d1 = fmaf(bf2f(v1[e]), xi[e], d1);
        }
#pragma unroll
        for (int off = 32; off; off >>= 1) {
            d0 += __shfl_xor(d0, off, 64);
            d1 += __shfl_xor(d1, off, 64);
        }
        if (lane == 0) {
            atomicAdd(&score[i * 256 + k], d0);
            if (h1) atomicAdd(&score[i * 256 + k1], d1);
        }
    }
}

// PV for one (i, slab): softmax re-derived per slab (trivial: ~42 exps), then
// out[i][slab] = sum_k p_k * xb[jk][slab]. Same XCD-pinned slab residency.
__global__ __launch_bounds__(256) void pv_slab(const short* __restrict__ xb,
                                               const float* __restrict__ nsq,
                                               const unsigned short* __restrict__ idx,
                                               const int* __restrict__ cnt,
                                               const float* __restrict__ score,
                                               const float* __restrict__ betaPtr,
                                               float* __restrict__ out) {
    __shared__ float sv[256];
    __shared__ unsigned short sidx[256];
    __shared__ float red[4][SLABC];
    const int t = threadIdx.x;
    const int lane = t & 63;
    const int w = t >> 6;
    const int col0 = blockIdx.x * SLABC;
    const size_t i = blockIdx.y;
    const int c = cnt[i];

    if (t < c) sidx[t] = idx[i * 256 + t];
    __syncthreads();

    if (w == 0) {  // scale + softmax (masked entries contribute exactly 0, as in ref)
        const float beta = *betaPtr;
        const float ni = sqrtf(nsq[i]);
        for (int k = lane; k < c; k += 64) {
            const int j = sidx[k];
            sv[k] = beta * score[i * 256 + k] / (ni * sqrtf(nsq[j]) + EPSV);
        }
        float mx = -3.0e38f;
        for (int k = lane; k < c; k += 64) mx = fmaxf(mx, sv[k]);
#pragma unroll
        for (int off = 32; off; off >>= 1) mx = fmaxf(mx, __shfl_xor(mx, off, 64));
        float sm = 0.f;
        for (int k = lane; k < c; k += 64) {
            float e = __expf(sv[k] - mx);
            sv[k] = e;
            sm += e;
        }
#pragma unroll
        for (int off = 32; off; off >>= 1) sm += __shfl_xor(sm, off, 64);
        const float inv = 1.f / sm;
        for (int k = lane; k < c; k += 64) sv[k] *= inv;
    }
    __syncthreads();

    // lane owns cols [col0+8l, col0+8l+8); wave w takes k = w, w+4, ... x2 unroll
    float acc[8];
#pragma unroll
    for (int e = 0; e < 8; ++e) acc[e] = 0.f;
    for (int k = w; k < c; k += 8) {
        const int k1 = k + 4;
        const bool h1 = k1 < c;
        const int j0 = sidx[k];
        const int j1 = h1 ? sidx[k1] : j0;
        const float p0 = sv[k];
        const float p1 = h1 ? sv[k1] : 0.f;
        short8 v0 = ((const short8*)(xb + (size_t)j0 * NN + col0))[lane];
        short8 v1 = ((const short8*)(xb + (size_t)j1 * NN + col0))[lane];
#pragma unroll
        for (int e = 0; e < 8; ++e) {
            acc[e] = fmaf(p0, bf2f(v0[e]), acc[e]);
            acc[e] = fmaf(p1, bf2f(v1[e]), acc[e]);
        }
    }
    // cross-wave reduce; column-major layout -> bank-conflict-free scalar writes
#pragma unroll
    for (int e = 0; e < 8; ++e) red[w][e * 64 + lane] = acc[e];
    __syncthreads();
    const int cA = 2 * t, cB = 2 * t + 1;
    const int iA = (cA & 7) * 64 + (cA >> 3);
    const int iB = (cB & 7) * 64 + (cB >> 3);
    floatx2 o = {red[0][iA] + red[1][iA] + red[2][iA] + red[3][iA],
                 red[0][iB] + red[1][iB] + red[2][iB] + red[3][iB]};
    __builtin_nontemporal_store(o, (floatx2*)(out + i * NN + col0 + 2 * t));
}

extern "C" void kernel_launch(void* const* d_in, const int* in_sizes, int n_in,
                              void* d_out, int out_size, void* d_ws, size_t ws_size,
                              hipStream_t stream) {
    const float* x = (const float*)d_in[0];
    const float* adj = (const float*)d_in[1];
    const float* beta = (const float*)d_in[2];

    const size_t XB = (size_t)32 * 1024 * 1024;  // bf16 x
    const size_t IX = (size_t)2 * 1024 * 1024;   // u16 idx [4096][256]
    const size_t SC = (size_t)4 * 1024 * 1024;   // f32 score [4096][256]
    const size_t need = XB + IX + SC + 2 * NN * sizeof(float);
    if (ws_size < need) return;  // ~38 MB

    char* ws = (char*)d_ws;
    short* xb = (short*)ws;
    unsigned short* idx = (unsigned short*)(ws + XB);
    float* score = (float*)(ws + XB + IX);
    float* nsq = (float*)(ws + XB + IX + SC);
    int* cnt = (int*)(ws + XB + IX + SC + NN * sizeof(float));

    (void)hipMemsetAsync(nsq, 0, NN * sizeof(float), stream);
    (void)hipMemsetAsync(score, 0, SC, stream);
    fuse_cast<<<dim3(16, 64), dim3(64, 4), 0, stream>>>(x, xb, nsq);
    build_idx<<<NN, 256, 0, stream>>>(adj, idx, cnt);
    score_slab<<<dim3(NSLAB, NN), 256, 0, stream>>>(xb, idx, cnt, score);
    pv_slab<<<dim3(NSLAB, NN), 256, 0, stream>>>(xb, nsq, idx, cnt, score, beta, (float*)d_out);
}

// Round 6
// 310.071 us; speedup vs baseline: 1.4536x; 1.3021x over previous
//
#include <hip/hip_runtime.h>
#include <stdint.h>

#define NN 4096
#define EPSV 1e-7f
#define SLABC 512          // columns per slab; 4096x512 f16 = 4 MB = one XCD L2
#define NSLAB (NN / SLABC) // 8 slabs = 8 XCDs

typedef short shortx4 __attribute__((ext_vector_type(4)));
typedef float floatx2 __attribute__((ext_vector_type(2)));
typedef float floatx4 __attribute__((ext_vector_type(4)));
typedef unsigned int uintx4 __attribute__((ext_vector_type(4)));
typedef _Float16 half2t __attribute__((ext_vector_type(2)));

static __device__ __forceinline__ short f2h(float f) {
    union { _Float16 h; short s; } c;
    c.h = (_Float16)f;
    return c.s;
}

// d += dot(2xf16(a), 2xf16(b)) via cvt+fma (folds to v_fma_mix_f32; no
// target-feature-gated builtins — __builtin_amdgcn_fdot2 does not compile
// for gfx950).
static __device__ __forceinline__ float dot2acc(unsigned a, unsigned b, float d) {
    union { unsigned u; half2t h; } ua, ub;
    ua.u = a; ub.u = b;
    d = fmaf((float)ua.h[0], (float)ub.h[0], d);
    return fmaf((float)ua.h[1], (float)ub.h[1], d);
}

// x (f32) -> xh (f16 row-major) + nsq (col sumsq). x never re-read -> nt loads.
// f16 serves BOTH score and PV: more mantissa than bf16, range safe (|x|~N(0,1)).
__global__ __launch_bounds__(256) void fuse_cast(const float* __restrict__ x,
                                                 short* __restrict__ xh,
                                                 float* __restrict__ nsq) {
    __shared__ floatx4 cs[4][64];
    const int tx = threadIdx.x;       // 0..63
    const int ty = threadIdx.y;       // 0..3
    const int cb = blockIdx.x * 256;  // 16 blocks cover 4096 cols
    const int rb = blockIdx.y * 64;   // 64 blocks cover 4096 rows
    const int col = cb + tx * 4;
    floatx4 ss = {0.f, 0.f, 0.f, 0.f};
#pragma unroll
    for (int i = 0; i < 16; ++i) {
        const int r = rb + ty + i * 4;
        floatx4 v = __builtin_nontemporal_load((const floatx4*)(x + (size_t)r * NN + col));
        ss += v * v;
        shortx4 o;
        o[0] = f2h(v[0]); o[1] = f2h(v[1]); o[2] = f2h(v[2]); o[3] = f2h(v[3]);
        *(shortx4*)(xh + (size_t)r * NN + col) = o;
    }
    cs[ty][tx] = ss;
    __syncthreads();
    if (ty == 0) {
        floatx4 s4 = cs[0][tx] + cs[1][tx] + cs[2][tx] + cs[3][tx];
        float* np = nsq + col;
        atomicAdd(np + 0, s4[0]);
        atomicAdd(np + 1, s4[1]);
        atomicAdd(np + 2, s4[2]);
        atomicAdd(np + 3, s4[3]);
    }
}

// adj row i -> sorted column-index list (prefix-sum compaction, deterministic).
// Thread t owns cols [16t, 16t+16). ~42 nnz/row; cap 256 is +33 sigma.
__global__ __launch_bounds__(256) void build_idx(const float* __restrict__ adj,
                                                 unsigned short* __restrict__ idx,
                                                 int* __restrict__ cnt) {
    __shared__ int wtot[4];
    const int t = threadIdx.x;
    const int lane = t & 63;
    const int w = t >> 6;
    const size_t i = blockIdx.x;
    const floatx4* ar = (const floatx4*)(adj + i * NN) + 4 * t;
    floatx4 a0 = __builtin_nontemporal_load(ar + 0);
    floatx4 a1 = __builtin_nontemporal_load(ar + 1);
    floatx4 a2 = __builtin_nontemporal_load(ar + 2);
    floatx4 a3 = __builtin_nontemporal_load(ar + 3);
    unsigned mask = 0;
#pragma unroll
    for (int u = 0; u < 4; ++u) {
        floatx4 a = (u == 0) ? a0 : (u == 1) ? a1 : (u == 2) ? a2 : a3;
#pragma unroll
        for (int e = 0; e < 4; ++e)
            if (a[e] != 0.f) mask |= 1u << (4 * u + e);
    }
    const int h = __popc(mask);
    int sc = h;  // wave-inclusive scan
#pragma unroll
    for (int o = 1; o < 64; o <<= 1) {
        int v = __shfl_up(sc, o, 64);
        if (lane >= o) sc += v;
    }
    if (lane == 63) wtot[w] = sc;
    __syncthreads();
    int base = 0;
#pragma unroll
    for (int ww = 0; ww < 4; ++ww)
        if (ww < w) base += wtot[ww];
    int c = wtot[0] + wtot[1] + wtot[2] + wtot[3];
    if (c > 256) c = 256;
    if (t == 0) cnt[i] = c;
    int off = base + sc - h;  // exclusive prefix
    unsigned m = mask;
    while (m) {
        int b = __ffs(m) - 1;
        m &= m - 1;
        if (off < 256) idx[i * 256 + off] = (unsigned short)(16 * t + b);
        ++off;
    }
}

// Partial scores for one (i-quad, slab). Wave w owns i = 4*by + w entirely:
// no LDS, no barriers. Within a wave: 8 groups x 8 lanes; group g computes k's
// = r*8+g; lane sl covers 64 cols (8 uintx4 chunks, all 8 loads in flight).
// Reduce = 3 xor steps over lanes 1/2/4, amortized over 8 k's.
// gridDim.x = NSLAB -> workgroup %8 -> XCD s only touches slab s (L2-resident).
__global__ __launch_bounds__(256) void score_slab(const short* __restrict__ xh,
                                                  const unsigned short* __restrict__ idx,
                                                  const int* __restrict__ cnt,
                                                  float* __restrict__ score) {
    const int t = threadIdx.x;
    const int lane = t & 63;
    const int w = t >> 6;
    const int g = lane >> 3;  // k-group within round
    const int sl = lane & 7;  // column sub-chunk
    const int col0 = blockIdx.x * SLABC;
    const size_t i = (size_t)blockIdx.y * 4 + w;
    const int c = cnt[i];
    const unsigned short* irow = idx + i * 256;

    const uintx4* xr = (const uintx4*)(xh + i * NN + col0);
    uintx4 xi[8];
#pragma unroll
    for (int it = 0; it < 8; ++it) xi[it] = xr[it * 8 + sl];

    for (int r = 0; r * 8 < c; ++r) {
        const int k = r * 8 + g;
        const bool ok = k < c;
        const int kk = ok ? k : c - 1;
        const int j = irow[kk];
        const uintx4* rp = (const uintx4*)(xh + (size_t)j * NN + col0);
        uintx4 v0 = rp[0 * 8 + sl], v1 = rp[1 * 8 + sl];
        uintx4 v2 = rp[2 * 8 + sl], v3 = rp[3 * 8 + sl];
        uintx4 v4 = rp[4 * 8 + sl], v5 = rp[5 * 8 + sl];
        uintx4 v6 = rp[6 * 8 + sl], v7 = rp[7 * 8 + sl];
        float d0 = 0.f, d1 = 0.f;
#pragma unroll
        for (int u = 0; u < 4; ++u) {
            d0 = dot2acc(v0[u], xi[0][u], d0);
            d1 = dot2acc(v1[u], xi[1][u], d1);
            d0 = dot2acc(v2[u], xi[2][u], d0);
            d1 = dot2acc(v3[u], xi[3][u], d1);
            d0 = dot2acc(v4[u], xi[4][u], d0);
            d1 = dot2acc(v5[u], xi[5][u], d1);
            d0 = dot2acc(v6[u], xi[6][u], d0);
            d1 = dot2acc(v7[u], xi[7][u], d1);
        }
        float d = d0 + d1;
        d += __shfl_xor(d, 1, 64);
        d += __shfl_xor(d, 2, 64);
        d += __shfl_xor(d, 4, 64);
        if (ok && sl == 0) atomicAdd(&score[i * 256 + k], d);
    }
}

// PV for one (i-quad, slab). Wave w owns i = 4*by + w: per-wave softmax
// (scores summed across slabs by score_slab's atomics), p/j staged in LDS,
// then lane owns cols [col0+8l, col0+8l+8), 4 k's in flight.
__global__ __launch_bounds__(256) void pv_slab(const short* __restrict__ xh,
                                               const float* __restrict__ nsq,
                                               const unsigned short* __restrict__ idx,
                                               const int* __restrict__ cnt,
                                               const float* __restrict__ score,
                                               const float* __restrict__ betaPtr,
                                               float* __restrict__ out) {
    __shared__ float svs[4][256];
    __shared__ unsigned short jds[4][256];
    const int t = threadIdx.x;
    const int lane = t & 63;
    const int w = t >> 6;
    const int col0 = blockIdx.x * SLABC;
    const size_t i = (size_t)blockIdx.y * 4 + w;
    const int c = cnt[i];
    const float beta = *betaPtr;
    const float ni = sqrtf(nsq[i]);

    // per-wave softmax over sv[0..c) (masked entries contribute exactly 0, as in ref)
    float sreg[4];
    int jreg[4];
#pragma unroll
    for (int q = 0; q < 4; ++q) {
        const int k = lane + 64 * q;
        if (k < c) {
            const int j = idx[i * 256 + k];
            jreg[q] = j;
            sreg[q] = beta * score[i * 256 + k] / (ni * sqrtf(nsq[j]) + EPSV);
        } else {
            jreg[q] = 0;
            sreg[q] = -3.0e38f;
        }
    }
    float mx = fmaxf(fmaxf(sreg[0], sreg[1]), fmaxf(sreg[2], sreg[3]));
#pragma unroll
    for (int off = 32; off; off >>= 1) mx = fmaxf(mx, __shfl_xor(mx, off, 64));
    float sm = 0.f;
#pragma unroll
    for (int q = 0; q < 4; ++q) {
        const int k = lane + 64 * q;
        float e = (k < c) ? __expf(sreg[q] - mx) : 0.f;
        sreg[q] = e;
        sm += e;
    }
#pragma unroll
    for (int off = 32; off; off >>= 1) sm += __shfl_xor(sm, off, 64);
    const float inv = 1.f / sm;
#pragma unroll
    for (int q = 0; q < 4; ++q) {
        const int k = lane + 64 * q;
        svs[w][k] = sreg[q] * inv;
        jds[w][k] = (unsigned short)jreg[q];
    }
    __syncthreads();  // uniform; fences LDS

    float acc[8];
#pragma unroll
    for (int e = 0; e < 8; ++e) acc[e] = 0.f;
    const short* xcol = xh + col0 + lane * 8;
    int k = 0;
    for (; k + 4 <= c; k += 4) {
        const int j0 = jds[w][k], j1 = jds[w][k + 1];
        const int j2 = jds[w][k + 2], j3 = jds[w][k + 3];
        const float p0 = svs[w][k], p1 = svs[w][k + 1];
        const float p2 = svs[w][k + 2], p3 = svs[w][k + 3];
        uintx4 v0 = *(const uintx4*)(xcol + (size_t)j0 * NN);
        uintx4 v1 = *(const uintx4*)(xcol + (size_t)j1 * NN);
        uintx4 v2 = *(const uintx4*)(xcol + (size_t)j2 * NN);
        uintx4 v3 = *(const uintx4*)(xcol + (size_t)j3 * NN);
#pragma unroll
        for (int u = 0; u < 4; ++u) {
            union { unsigned x; half2t h; } c0, c1, c2, c3;
            c0.x = v0[u]; c1.x = v1[u]; c2.x = v2[u]; c3.x = v3[u];
            float a0 = acc[2 * u], a1 = acc[2 * u + 1];
            a0 = fmaf(p0, (float)c0.h[0], a0); a1 = fmaf(p0, (float)c0.h[1], a1);
            a0 = fmaf(p1, (float)c1.h[0], a0); a1 = fmaf(p1, (float)c1.h[1], a1);
            a0 = fmaf(p2, (float)c2.h[0], a0); a1 = fmaf(p2, (float)c2.h[1], a1);
            a0 = fmaf(p3, (float)c3.h[0], a0); a1 = fmaf(p3, (float)c3.h[1], a1);
            acc[2 * u] = a0; acc[2 * u + 1] = a1;
        }
    }
    for (; k < c; ++k) {
        const int j = jds[w][k];
        const float p = svs[w][k];
        uintx4 v = *(const uintx4*)(xcol + (size_t)j * NN);
#pragma unroll
        for (int u = 0; u < 4; ++u) {
            union { unsigned x; half2t h; } cc;
            cc.x = v[u];
            acc[2 * u] = fmaf(p, (float)cc.h[0], acc[2 * u]);
            acc[2 * u + 1] = fmaf(p, (float)cc.h[1], acc[2 * u + 1]);
        }
    }
    floatx4* op = (floatx4*)(out + i * NN + col0 + lane * 8);
    floatx4 o0 = {acc[0], acc[1], acc[2], acc[3]};
    floatx4 o1 = {acc[4], acc[5], acc[6], acc[7]};
    __builtin_nontemporal_store(o0, op + 0);
    __builtin_nontemporal_store(o1, op + 1);
}

extern "C" void kernel_launch(void* const* d_in, const int* in_sizes, int n_in,
                              void* d_out, int out_size, void* d_ws, size_t ws_size,
                              hipStream_t stream) {
    const float* x = (const float*)d_in[0];
    const float* adj = (const float*)d_in[1];
    const float* beta = (const float*)d_in[2];

    const size_t XH = (size_t)32 * 1024 * 1024;  // f16 x
    const size_t IX = (size_t)2 * 1024 * 1024;   // u16 idx [4096][256]
    const size_t SC = (size_t)4 * 1024 * 1024;   // f32 score [4096][256]
    const size_t need = XH + IX + SC + 2 * NN * sizeof(float);
    if (ws_size < need) return;  // ~38 MB

    char* ws = (char*)d_ws;
    short* xh = (short*)ws;
    unsigned short* idx = (unsigned short*)(ws + XH);
    float* score = (float*)(ws + XH + IX);
    float* nsq = (float*)(ws + XH + IX + SC);
    int* cnt = (int*)(ws + XH + IX + SC + NN * sizeof(float));

    (void)hipMemsetAsync(nsq, 0, NN * sizeof(float), stream);
    (void)hipMemsetAsync(score, 0, SC, stream);
    fuse_cast<<<dim3(16, 64), dim3(64, 4), 0, stream>>>(x, xh, nsq);
    build_idx<<<NN, 256, 0, stream>>>(adj, idx, cnt);
    score_slab<<<dim3(NSLAB, NN / 4), 256, 0, stream>>>(xh, idx, cnt, score);
    pv_slab<<<dim3(NSLAB, NN / 4), 256, 0, stream>>>(xh, nsq, idx, cnt, score, beta, (float*)d_out);
}